// Round 1
// baseline (1900.813 us; speedup 1.0000x reference)
//
#include <hip/hip_runtime.h>
#include <hip/hip_bf16.h>
#include <math.h>

// EnvelopeWassersteinLoss: n=m=8192, d=64, EPS=0.05, 20 Sinkhorn iterations.
// Strategy:
//   prep:    XP,XQ f32 -> bf16 copies + row sq-norms (pn,qn)
//   gemm_max: MFMA bf16 GEMM (no stores) -> atomicMax of C  => reg = 0.05*maxC
//   gemm_K:  recompute GEMM, K = exp(-C/reg) stored bf16 row-major (128MB, L3-fits)
//   20x:     matvecT (y_part = K^T u, 64 row-chunk partials)
//            reduce_v (v = b / sum(y_part))
//            matvecR (x = K v, final per-row via wave reduce)
//            u = a/x is computed on-the-fly by consumers.
//   loss:    sum_ij u_i * K_ij * v_j * (-reg * ln K_ij)  -> atomicAdd to d_out

#define NN 8192
#define DD 64
#define EPSV 0.05f
#define NITER 20

typedef __attribute__((ext_vector_type(8))) short short8;   // 8 x bf16
typedef __attribute__((ext_vector_type(4))) float fx4;      // MFMA acc

__device__ inline float bf2f(unsigned short u) {
    union { unsigned int i; float f; } x; x.i = ((unsigned int)u) << 16; return x.f;
}
__device__ inline unsigned short f2bf(float f) {
    union { float f; unsigned int i; } x; x.f = f;
    unsigned int r = x.i + 0x7fffu + ((x.i >> 16) & 1u);   // round-to-nearest-even
    return (unsigned short)(r >> 16);
}

// ---------------- prep: convert + row norms ----------------
__global__ __launch_bounds__(256) void prep_k(const float* __restrict__ XP,
                                              const float* __restrict__ XQ,
                                              unsigned short* __restrict__ XPb,
                                              unsigned short* __restrict__ XQb,
                                              float* __restrict__ pn,
                                              float* __restrict__ qn) {
    int task = blockIdx.x * 4 + (threadIdx.x >> 6);
    int lane = threadIdx.x & 63;
    const float* src; unsigned short* dst; float* nrm; int row;
    if (task < NN) { src = XP; dst = XPb; nrm = pn; row = task; }
    else           { src = XQ; dst = XQb; nrm = qn; row = task - NN; }
    float xv = src[row * DD + lane];
    dst[row * DD + lane] = f2bf(xv);
    float s = xv * xv;
    #pragma unroll
    for (int o = 32; o; o >>= 1) s += __shfl_xor(s, o);
    if (lane == 0) nrm[row] = s;
}

__global__ void init_k(unsigned int* maxbits, float* out) {
    if (threadIdx.x == 0) { *maxbits = 0u; out[0] = 0.0f; }
}

// ---------------- shared GEMM tile: wave computes 64x64 via 4x4 MFMA frags ----------------
__device__ inline void gemm_tile(const unsigned short* __restrict__ XPb,
                                 const unsigned short* __restrict__ XQb,
                                 int R0, int C0, int lane, fx4 acc[4][4]) {
    int r  = lane & 15;
    int ko = (lane >> 4) * 8;
    #pragma unroll
    for (int kk = 0; kk < DD; kk += 32) {
        short8 a[4], b[4];
        #pragma unroll
        for (int m = 0; m < 4; m++)
            a[m] = *(const short8*)(XPb + (R0 + m * 16 + r) * DD + kk + ko);
        #pragma unroll
        for (int n = 0; n < 4; n++)
            b[n] = *(const short8*)(XQb + (C0 + n * 16 + r) * DD + kk + ko);
        #pragma unroll
        for (int m = 0; m < 4; m++)
            #pragma unroll
            for (int n = 0; n < 4; n++)
                acc[m][n] = __builtin_amdgcn_mfma_f32_16x16x32_bf16(a[m], b[n], acc[m][n], 0, 0, 0);
    }
}

// ---------------- pass 1: global max of C ----------------
__global__ __launch_bounds__(256) void gemm_max_k(const unsigned short* __restrict__ XPb,
                                                  const unsigned short* __restrict__ XQb,
                                                  const float* __restrict__ pn,
                                                  const float* __restrict__ qn,
                                                  unsigned int* __restrict__ maxbits) {
    int w = threadIdx.x >> 6, wr = w >> 1, wc = w & 1;
    int lane = threadIdx.x & 63;
    int R0 = blockIdx.y * 128 + wr * 64;
    int C0 = blockIdx.x * 128 + wc * 64;
    fx4 acc[4][4] = {};
    gemm_tile(XPb, XQb, R0, C0, lane, acc);

    float pl = pn[R0 + lane], ql = qn[C0 + lane];
    float pr[16], qc[4];
    #pragma unroll
    for (int m = 0; m < 4; m++)
        #pragma unroll
        for (int j = 0; j < 4; j++)
            pr[m * 4 + j] = __shfl(pl, m * 16 + ((lane >> 4) << 2) + j);
    #pragma unroll
    for (int n = 0; n < 4; n++) qc[n] = __shfl(ql, n * 16 + (lane & 15));

    float mx = 0.0f;
    #pragma unroll
    for (int m = 0; m < 4; m++)
        #pragma unroll
        for (int n = 0; n < 4; n++)
            #pragma unroll
            for (int j = 0; j < 4; j++)
                mx = fmaxf(mx, pr[m * 4 + j] + qc[n] - 2.0f * acc[m][n][j]);
    #pragma unroll
    for (int o = 32; o; o >>= 1) mx = fmaxf(mx, __shfl_xor(mx, o));
    if (lane == 0) atomicMax(maxbits, __float_as_uint(mx));  // C >= 0: uint-compare == float-compare
}

// ---------------- pass 2: K = exp(-C/reg) in bf16 ----------------
__global__ __launch_bounds__(256) void gemm_K_k(const unsigned short* __restrict__ XPb,
                                                const unsigned short* __restrict__ XQb,
                                                const float* __restrict__ pn,
                                                const float* __restrict__ qn,
                                                const unsigned int* __restrict__ maxbits,
                                                unsigned short* __restrict__ Kb) {
    int w = threadIdx.x >> 6, wr = w >> 1, wc = w & 1;
    int lane = threadIdx.x & 63;
    int R0 = blockIdx.y * 128 + wr * 64;
    int C0 = blockIdx.x * 128 + wc * 64;
    fx4 acc[4][4] = {};
    gemm_tile(XPb, XQb, R0, C0, lane, acc);

    float inv_reg = 1.0f / (EPSV * __uint_as_float(*maxbits));
    float pl = pn[R0 + lane], ql = qn[C0 + lane];
    float pr[16], qc[4];
    #pragma unroll
    for (int m = 0; m < 4; m++)
        #pragma unroll
        for (int j = 0; j < 4; j++)
            pr[m * 4 + j] = __shfl(pl, m * 16 + ((lane >> 4) << 2) + j);
    #pragma unroll
    for (int n = 0; n < 4; n++) qc[n] = __shfl(ql, n * 16 + (lane & 15));

    #pragma unroll
    for (int m = 0; m < 4; m++) {
        #pragma unroll
        for (int n = 0; n < 4; n++) {
            #pragma unroll
            for (int j = 0; j < 4; j++) {
                float c = fmaxf(pr[m * 4 + j] + qc[n] - 2.0f * acc[m][n][j], 0.0f);
                float kv = __expf(-c * inv_reg);
                int row = R0 + m * 16 + ((lane >> 4) << 2) + j;
                int col = C0 + n * 16 + (lane & 15);
                Kb[(size_t)row * NN + col] = f2bf(kv);
            }
        }
    }
}

// ---------------- y_part[rc][j] = sum_{i in chunk rc} K[i][j] * u_i ----------------
// grid (16 col-chunks, 64 row-chunks), 64 threads. u_i = a/x_i (or 1/N at iter 0).
__global__ __launch_bounds__(64) void matvecT_k(const unsigned short* __restrict__ Kb,
                                                const float* __restrict__ x,
                                                float* __restrict__ y_part, int iter) {
    int lane = threadIdx.x;
    int col0 = blockIdx.x * 512 + lane * 8;
    int r0 = blockIdx.y * 128;
    float ua, ub;
    if (iter == 0) { ua = ub = 1.0f / (float)NN; }
    else { ua = (1.0f / (float)NN) / x[r0 + lane]; ub = (1.0f / (float)NN) / x[r0 + 64 + lane]; }

    float av[8] = {0, 0, 0, 0, 0, 0, 0, 0};
    const unsigned short* base = Kb + (size_t)r0 * NN + col0;
    #pragma unroll 4
    for (int rr = 0; rr < 128; ++rr) {
        float ui = __shfl((rr < 64) ? ua : ub, rr & 63);
        short8 kv = *(const short8*)(base + (size_t)rr * NN);
        #pragma unroll
        for (int e = 0; e < 8; e++) av[e] += bf2f((unsigned short)kv[e]) * ui;
    }
    float* yp = y_part + (size_t)blockIdx.y * NN + col0;
    fx4 s0 = {av[0], av[1], av[2], av[3]};
    fx4 s1 = {av[4], av[5], av[6], av[7]};
    *(fx4*)(yp)     = s0;
    *(fx4*)(yp + 4) = s1;
}

// ---------------- v[j] = b / sum_rc y_part[rc][j] ----------------
__global__ __launch_bounds__(256) void reduce_v_k(const float* __restrict__ y_part,
                                                  float* __restrict__ vv) {
    int j = blockIdx.x * 256 + threadIdx.x;
    float s = 0.0f;
    #pragma unroll 8
    for (int rc = 0; rc < 64; ++rc) s += y_part[(size_t)rc * NN + j];
    vv[j] = (1.0f / (float)NN) / s;
}

// ---------------- x[i] = sum_j K[i][j] * v[j] ----------------
// grid 256 blocks x 256 threads; block = 32 rows, wave = 8 rows.
__global__ __launch_bounds__(256) void matvecR_k(const unsigned short* __restrict__ Kb,
                                                 const float* __restrict__ vv,
                                                 float* __restrict__ x) {
    int w = threadIdx.x >> 6, lane = threadIdx.x & 63;
    int rbase = blockIdx.x * 32 + w * 8;
    for (int rr = 0; rr < 8; ++rr) {
        int i = rbase + rr;
        const unsigned short* Krow = Kb + (size_t)i * NN;
        float a0 = 0.0f, a1 = 0.0f;
        #pragma unroll 4
        for (int p = 0; p < 16; ++p) {
            int c0 = p * 512 + lane * 8;
            short8 kv = *(const short8*)(Krow + c0);
            fx4 v0 = *(const fx4*)(vv + c0);
            fx4 v1 = *(const fx4*)(vv + c0 + 4);
            a0 += bf2f((unsigned short)kv[0]) * v0[0];
            a1 += bf2f((unsigned short)kv[1]) * v0[1];
            a0 += bf2f((unsigned short)kv[2]) * v0[2];
            a1 += bf2f((unsigned short)kv[3]) * v0[3];
            a0 += bf2f((unsigned short)kv[4]) * v1[0];
            a1 += bf2f((unsigned short)kv[5]) * v1[1];
            a0 += bf2f((unsigned short)kv[6]) * v1[2];
            a1 += bf2f((unsigned short)kv[7]) * v1[3];
        }
        float acc = a0 + a1;
        #pragma unroll
        for (int o = 32; o; o >>= 1) acc += __shfl_xor(acc, o);
        if (lane == 0) x[i] = acc;
    }
}

// ---------------- loss = sum_ij u_i K_ij v_j * (-reg ln K_ij) ----------------
__global__ __launch_bounds__(256) void loss_k(const unsigned short* __restrict__ Kb,
                                              const float* __restrict__ vv,
                                              const float* __restrict__ x,
                                              const unsigned int* __restrict__ maxbits,
                                              float* __restrict__ out) {
    float reg = EPSV * __uint_as_float(*maxbits);
    int w = threadIdx.x >> 6, lane = threadIdx.x & 63;
    int rbase = blockIdx.x * 32 + w * 8;
    float lacc = 0.0f;
    for (int rr = 0; rr < 8; ++rr) {
        int i = rbase + rr;
        float ui = (1.0f / (float)NN) / x[i];
        const unsigned short* Krow = Kb + (size_t)i * NN;
        float t0 = 0.0f, t1 = 0.0f;
        #pragma unroll 2
        for (int p = 0; p < 16; ++p) {
            int c0 = p * 512 + lane * 8;
            short8 kv = *(const short8*)(Krow + c0);
            fx4 v0 = *(const fx4*)(vv + c0);
            fx4 v1 = *(const fx4*)(vv + c0 + 4);
            #pragma unroll
            for (int e = 0; e < 4; e++) {
                float k0 = bf2f((unsigned short)kv[e]);
                float k1 = bf2f((unsigned short)kv[e + 4]);
                float c0f = -reg * __logf(k0);
                float c1f = -reg * __logf(k1);
                t0 += k0 * c0f * v0[e];
                t1 += k1 * c1f * v1[e];
            }
        }
        lacc += ui * (t0 + t1);
    }
    #pragma unroll
    for (int o = 32; o; o >>= 1) lacc += __shfl_xor(lacc, o);
    __shared__ float wsum[4];
    if (lane == 0) wsum[w] = lacc;
    __syncthreads();
    if (threadIdx.x == 0) atomicAdd(out, wsum[0] + wsum[1] + wsum[2] + wsum[3]);
}

extern "C" void kernel_launch(void* const* d_in, const int* in_sizes, int n_in,
                              void* d_out, int out_size, void* d_ws, size_t ws_size,
                              hipStream_t stream) {
    const float* XP = (const float*)d_in[0];
    const float* XQ = (const float*)d_in[1];
    float* out = (float*)d_out;

    // workspace layout (~132.2 MiB total)
    char* w = (char*)d_ws;
    unsigned short* Kb  = (unsigned short*)w;                         // 8192*8192*2 = 128 MiB
    unsigned short* XPb = (unsigned short*)(w + (size_t)NN * NN * 2); // 1 MiB
    unsigned short* XQb = XPb + NN * DD;                              // 1 MiB
    float* pn = (float*)(XQb + NN * DD);                              // 32 KiB
    float* qn = pn + NN;                                              // 32 KiB
    float* x  = qn + NN;                                              // 32 KiB
    float* vv = x + NN;                                               // 32 KiB
    float* y_part = vv + NN;                                          // 64*8192*4 = 2 MiB
    unsigned int* maxbits = (unsigned int*)(y_part + 64 * NN);

    prep_k<<<4096, 256, 0, stream>>>(XP, XQ, XPb, XQb, pn, qn);
    init_k<<<1, 64, 0, stream>>>(maxbits, out);
    gemm_max_k<<<dim3(64, 64), 256, 0, stream>>>(XPb, XQb, pn, qn, maxbits);
    gemm_K_k<<<dim3(64, 64), 256, 0, stream>>>(XPb, XQb, pn, qn, maxbits, Kb);

    for (int it = 0; it < NITER; ++it) {
        matvecT_k<<<dim3(16, 64), 64, 0, stream>>>(Kb, x, y_part, it);
        reduce_v_k<<<32, 256, 0, stream>>>(y_part, vv);
        matvecR_k<<<256, 256, 0, stream>>>(Kb, vv, x);
    }
    loss_k<<<256, 256, 0, stream>>>(Kb, vv, x, maxbits, out);
}

// Round 2
// 1181.721 us; speedup vs baseline: 1.6085x; 1.6085x over previous
//
#include <hip/hip_runtime.h>
#include <hip/hip_bf16.h>
#include <math.h>

// EnvelopeWassersteinLoss: n=m=8192, d=64, EPS=0.05, 20 Sinkhorn iterations.
//   prep:     XP,XQ f32 -> bf16 + row sq-norms
//   gemm_max: MFMA GEMM -> per-block max -> bm[] (no atomics)
//   max_red:  bm[4096] -> reg, inv_reg
//   gemm_K:   GEMM again, K=exp(-C/reg) bf16, LDS-transposed coalesced stores
//   20x:      matvecT (y_part = K^T u, 256 row-chunks), reduce_v (v=b/y),
//             matvecR (x = K v; last iter also t_i = sum_j K ln(K) v_j)
//   final:    out = sum_i (a/x_i) * (-reg) * t_i

#define NN 8192
#define DD 64
#define EPSV 0.05f
#define NITER 20

typedef __attribute__((ext_vector_type(8))) short short8;   // 8 x bf16
typedef __attribute__((ext_vector_type(4))) float fx4;

__device__ inline float bf2f(unsigned short u) {
    union { unsigned int i; float f; } x; x.i = ((unsigned int)u) << 16; return x.f;
}
__device__ inline unsigned short f2bf(float f) {
    union { float f; unsigned int i; } x; x.f = f;
    unsigned int r = x.i + 0x7fffu + ((x.i >> 16) & 1u);
    return (unsigned short)(r >> 16);
}

// ---------------- prep: convert + row norms ----------------
__global__ __launch_bounds__(256) void prep_k(const float* __restrict__ XP,
                                              const float* __restrict__ XQ,
                                              unsigned short* __restrict__ XPb,
                                              unsigned short* __restrict__ XQb,
                                              float* __restrict__ pn,
                                              float* __restrict__ qn) {
    int task = blockIdx.x * 4 + (threadIdx.x >> 6);
    int lane = threadIdx.x & 63;
    const float* src; unsigned short* dst; float* nrm; int row;
    if (task < NN) { src = XP; dst = XPb; nrm = pn; row = task; }
    else           { src = XQ; dst = XQb; nrm = qn; row = task - NN; }
    float xv = src[row * DD + lane];
    dst[row * DD + lane] = f2bf(xv);
    float s = xv * xv;
    #pragma unroll
    for (int o = 32; o; o >>= 1) s += __shfl_xor(s, o);
    if (lane == 0) nrm[row] = s;
}

// ---------------- shared GEMM tile: wave computes 64x64 via 4x4 MFMA frags ----------------
__device__ inline void gemm_tile(const unsigned short* __restrict__ XPb,
                                 const unsigned short* __restrict__ XQb,
                                 int R0, int C0, int lane, fx4 acc[4][4]) {
    int r  = lane & 15;
    int ko = (lane >> 4) * 8;
    #pragma unroll
    for (int kk = 0; kk < DD; kk += 32) {
        short8 a[4], b[4];
        #pragma unroll
        for (int m = 0; m < 4; m++)
            a[m] = *(const short8*)(XPb + (R0 + m * 16 + r) * DD + kk + ko);
        #pragma unroll
        for (int n = 0; n < 4; n++)
            b[n] = *(const short8*)(XQb + (C0 + n * 16 + r) * DD + kk + ko);
        #pragma unroll
        for (int m = 0; m < 4; m++)
            #pragma unroll
            for (int n = 0; n < 4; n++)
                acc[m][n] = __builtin_amdgcn_mfma_f32_16x16x32_bf16(a[m], b[n], acc[m][n], 0, 0, 0);
    }
}

// ---------------- pass 1: per-block max of C -> bm[] ----------------
__global__ __launch_bounds__(256) void gemm_max_k(const unsigned short* __restrict__ XPb,
                                                  const unsigned short* __restrict__ XQb,
                                                  const float* __restrict__ pn,
                                                  const float* __restrict__ qn,
                                                  float* __restrict__ bm) {
    int w = threadIdx.x >> 6, wr = w >> 1, wc = w & 1;
    int lane = threadIdx.x & 63;
    int R0 = blockIdx.y * 128 + wr * 64;
    int C0 = blockIdx.x * 128 + wc * 64;
    fx4 acc[4][4] = {};
    gemm_tile(XPb, XQb, R0, C0, lane, acc);

    float pl = pn[R0 + lane], ql = qn[C0 + lane];
    float pr[16], qc[4];
    #pragma unroll
    for (int m = 0; m < 4; m++)
        #pragma unroll
        for (int j = 0; j < 4; j++)
            pr[m * 4 + j] = __shfl(pl, m * 16 + ((lane >> 4) << 2) + j);
    #pragma unroll
    for (int n = 0; n < 4; n++) qc[n] = __shfl(ql, n * 16 + (lane & 15));

    float mx = 0.0f;
    #pragma unroll
    for (int m = 0; m < 4; m++)
        #pragma unroll
        for (int n = 0; n < 4; n++)
            #pragma unroll
            for (int j = 0; j < 4; j++)
                mx = fmaxf(mx, pr[m * 4 + j] + qc[n] - 2.0f * acc[m][n][j]);
    #pragma unroll
    for (int o = 32; o; o >>= 1) mx = fmaxf(mx, __shfl_xor(mx, o));
    __shared__ float wmax[4];
    if (lane == 0) wmax[w] = mx;
    __syncthreads();
    if (threadIdx.x == 0)
        bm[blockIdx.y * 64 + blockIdx.x] = fmaxf(fmaxf(wmax[0], wmax[1]), fmaxf(wmax[2], wmax[3]));
}

// ---------------- reduce bm[4096] -> regbuf {reg, inv_reg} ----------------
__global__ __launch_bounds__(256) void max_red_k(const float* __restrict__ bm,
                                                 float* __restrict__ regbuf) {
    int t = threadIdx.x;
    float mx = 0.0f;
    #pragma unroll
    for (int i = 0; i < 16; ++i) mx = fmaxf(mx, bm[i * 256 + t]);
    #pragma unroll
    for (int o = 32; o; o >>= 1) mx = fmaxf(mx, __shfl_xor(mx, o));
    __shared__ float wmax[4];
    if ((t & 63) == 0) wmax[t >> 6] = mx;
    __syncthreads();
    if (t == 0) {
        float m = fmaxf(fmaxf(wmax[0], wmax[1]), fmaxf(wmax[2], wmax[3]));
        float reg = EPSV * m;
        regbuf[0] = reg;
        regbuf[1] = 1.0f / reg;
    }
}

// ---------------- pass 2: K = exp(-C/reg), LDS-staged coalesced stores ----------------
__global__ __launch_bounds__(256) void gemm_K_k(const unsigned short* __restrict__ XPb,
                                                const unsigned short* __restrict__ XQb,
                                                const float* __restrict__ pn,
                                                const float* __restrict__ qn,
                                                const float* __restrict__ regbuf,
                                                unsigned short* __restrict__ Kb) {
    __shared__ unsigned short tile[128][136];   // stride 272B: 16B-aligned rows, ~2-way banks
    int w = threadIdx.x >> 6, wr = w >> 1, wc = w & 1;
    int lane = threadIdx.x & 63;
    int R0 = blockIdx.y * 128 + wr * 64;
    int C0 = blockIdx.x * 128 + wc * 64;
    fx4 acc[4][4] = {};
    gemm_tile(XPb, XQb, R0, C0, lane, acc);

    float inv_reg = regbuf[1];
    float pl = pn[R0 + lane], ql = qn[C0 + lane];
    float pr[16], qc[4];
    #pragma unroll
    for (int m = 0; m < 4; m++)
        #pragma unroll
        for (int j = 0; j < 4; j++)
            pr[m * 4 + j] = __shfl(pl, m * 16 + ((lane >> 4) << 2) + j);
    #pragma unroll
    for (int n = 0; n < 4; n++) qc[n] = __shfl(ql, n * 16 + (lane & 15));

    #pragma unroll
    for (int m = 0; m < 4; m++) {
        #pragma unroll
        for (int n = 0; n < 4; n++) {
            #pragma unroll
            for (int j = 0; j < 4; j++) {
                float c = fmaxf(pr[m * 4 + j] + qc[n] - 2.0f * acc[m][n][j], 0.0f);
                float kv = __expf(-c * inv_reg);
                int lr = wr * 64 + m * 16 + ((lane >> 4) << 2) + j;
                int lc = wc * 64 + n * 16 + (lane & 15);
                tile[lr][lc] = f2bf(kv);
            }
        }
    }
    __syncthreads();

    // coalesced store: each instr = 4 rows x 256B contiguous per wave
    int lane16 = threadIdx.x & 15;
    int rowgrp = threadIdx.x >> 4;            // 0..15
    size_t Rg = (size_t)blockIdx.y * 128;
    int Cg = blockIdx.x * 128;
    #pragma unroll
    for (int s = 0; s < 8; ++s) {
        int row = s * 16 + rowgrp;
        short8 vv8 = *(const short8*)&tile[row][lane16 * 8];
        *(short8*)(Kb + (Rg + row) * NN + Cg + lane16 * 8) = vv8;
    }
}

// ---------------- y_part[c][j] = sum_{i in 32-row chunk c} K[i][j] * u_i ----------------
__global__ __launch_bounds__(256) void matvecT_k(const unsigned short* __restrict__ Kb,
                                                 const float* __restrict__ x,
                                                 float* __restrict__ y_part, int iter) {
    __shared__ float us[32];
    int t = threadIdx.x;
    int r0 = blockIdx.y * 32;
    if (t < 32) {
        float u = 1.0f / (float)NN;
        if (iter != 0) u = u / x[r0 + t];
        us[t] = u;
    }
    __syncthreads();

    int col0 = blockIdx.x * 2048 + t * 8;
    float a0 = 0, a1 = 0, a2 = 0, a3 = 0, a4 = 0, a5 = 0, a6 = 0, a7 = 0;
    const unsigned short* base = Kb + (size_t)r0 * NN + col0;
    #pragma unroll 4
    for (int rr = 0; rr < 32; ++rr) {
        short8 kv = *(const short8*)(base + (size_t)rr * NN);
        float u = us[rr];
        a0 += bf2f((unsigned short)kv[0]) * u;
        a1 += bf2f((unsigned short)kv[1]) * u;
        a2 += bf2f((unsigned short)kv[2]) * u;
        a3 += bf2f((unsigned short)kv[3]) * u;
        a4 += bf2f((unsigned short)kv[4]) * u;
        a5 += bf2f((unsigned short)kv[5]) * u;
        a6 += bf2f((unsigned short)kv[6]) * u;
        a7 += bf2f((unsigned short)kv[7]) * u;
    }
    float* yp = y_part + (size_t)blockIdx.y * NN + col0;
    fx4 s0 = {a0, a1, a2, a3};
    fx4 s1 = {a4, a5, a6, a7};
    *(fx4*)(yp)     = s0;
    *(fx4*)(yp + 4) = s1;
}

// ---------------- v[j] = b / sum_c y_part[c][j] ----------------
// 128 blocks x 256 threads; block covers 64 cols; wave w sums chunks [64w,64w+64)
__global__ __launch_bounds__(256) void reduce_v_k(const float* __restrict__ y_part,
                                                  float* __restrict__ vv) {
    int t = threadIdx.x;
    int w = t >> 6;
    int j = blockIdx.x * 64 + (t & 63);
    float s = 0.0f;
    #pragma unroll 8
    for (int c = 0; c < 64; ++c)
        s += y_part[(size_t)(w * 64 + c) * NN + j];
    __shared__ float part[4][64];
    part[w][t & 63] = s;
    __syncthreads();
    if (t < 64) {
        float y = part[0][t] + part[1][t] + part[2][t] + part[3][t];
        vv[blockIdx.x * 64 + t] = (1.0f / (float)NN) / y;
    }
}

// ---------------- x[i] = sum_j K[i][j] v[j]; last iter also t[i] = sum K lnK v ----------------
__global__ __launch_bounds__(256) void matvecR_k(const unsigned short* __restrict__ Kb,
                                                 const float* __restrict__ vv,
                                                 float* __restrict__ x,
                                                 float* __restrict__ tt, int last) {
    int w = threadIdx.x >> 6, lane = threadIdx.x & 63;
    int rbase = blockIdx.x * 16 + w * 4;
    for (int rr = 0; rr < 4; ++rr) {
        int i = rbase + rr;
        const unsigned short* Krow = Kb + (size_t)i * NN;
        float acc = 0.0f, tacc = 0.0f;
        #pragma unroll 4
        for (int p = 0; p < 16; ++p) {
            int c0 = p * 512 + lane * 8;
            short8 kv = *(const short8*)(Krow + c0);
            fx4 v0 = *(const fx4*)(vv + c0);
            fx4 v1 = *(const fx4*)(vv + c0 + 4);
            if (last) {
                #pragma unroll
                for (int e = 0; e < 4; e++) {
                    float k0 = bf2f((unsigned short)kv[e]);
                    float k1 = bf2f((unsigned short)kv[e + 4]);
                    acc  += k0 * v0[e] + k1 * v1[e];
                    tacc += k0 * __logf(k0) * v0[e] + k1 * __logf(k1) * v1[e];
                }
            } else {
                #pragma unroll
                for (int e = 0; e < 4; e++) {
                    acc += bf2f((unsigned short)kv[e]) * v0[e]
                         + bf2f((unsigned short)kv[e + 4]) * v1[e];
                }
            }
        }
        #pragma unroll
        for (int o = 32; o; o >>= 1) acc += __shfl_xor(acc, o);
        if (last) {
            #pragma unroll
            for (int o = 32; o; o >>= 1) tacc += __shfl_xor(tacc, o);
        }
        if (lane == 0) {
            x[i] = acc;
            if (last) tt[i] = tacc;
        }
    }
}

// ---------------- out = sum_i (a/x_i) * (-reg) * t_i ----------------
__global__ __launch_bounds__(256) void final_loss_k(const float* __restrict__ x,
                                                    const float* __restrict__ tt,
                                                    const float* __restrict__ regbuf,
                                                    float* __restrict__ out) {
    int t = threadIdx.x;
    float s = 0.0f;
    for (int i = t; i < NN; i += 256)
        s += tt[i] / x[i];
    #pragma unroll
    for (int o = 32; o; o >>= 1) s += __shfl_xor(s, o);
    __shared__ float wsum[4];
    if ((t & 63) == 0) wsum[t >> 6] = s;
    __syncthreads();
    if (t == 0)
        out[0] = (wsum[0] + wsum[1] + wsum[2] + wsum[3]) * (-regbuf[0]) / (float)NN;
}

extern "C" void kernel_launch(void* const* d_in, const int* in_sizes, int n_in,
                              void* d_out, int out_size, void* d_ws, size_t ws_size,
                              hipStream_t stream) {
    const float* XP = (const float*)d_in[0];
    const float* XQ = (const float*)d_in[1];
    float* out = (float*)d_out;

    // workspace layout (~145 MiB)
    char* p = (char*)d_ws;
    unsigned short* Kb  = (unsigned short*)p;  p += (size_t)NN * NN * 2;   // 128 MiB
    unsigned short* XPb = (unsigned short*)p;  p += (size_t)NN * DD * 2;   // 1 MiB
    unsigned short* XQb = (unsigned short*)p;  p += (size_t)NN * DD * 2;   // 1 MiB
    float* y_part = (float*)p;                 p += (size_t)256 * NN * 4;  // 8 MiB
    float* pn = (float*)p;                     p += NN * 4;
    float* qn = (float*)p;                     p += NN * 4;
    float* x  = (float*)p;                     p += NN * 4;
    float* vv = (float*)p;                     p += NN * 4;
    float* tt = (float*)p;                     p += NN * 4;
    float* bm = (float*)p;                     p += 4096 * 4;
    float* regbuf = (float*)p;

    prep_k<<<4096, 256, 0, stream>>>(XP, XQ, XPb, XQb, pn, qn);
    gemm_max_k<<<dim3(64, 64), 256, 0, stream>>>(XPb, XQb, pn, qn, bm);
    max_red_k<<<1, 256, 0, stream>>>(bm, regbuf);
    gemm_K_k<<<dim3(64, 64), 256, 0, stream>>>(XPb, XQb, pn, qn, regbuf, Kb);

    for (int it = 0; it < NITER; ++it) {
        matvecT_k<<<dim3(4, 256), 256, 0, stream>>>(Kb, x, y_part, it);
        reduce_v_k<<<128, 256, 0, stream>>>(y_part, vv);
        matvecR_k<<<512, 256, 0, stream>>>(Kb, vv, x, tt, (it == NITER - 1) ? 1 : 0);
    }
    final_loss_k<<<1, 256, 0, stream>>>(x, tt, regbuf, out);
}

// Round 4
// 910.330 us; speedup vs baseline: 2.0880x; 1.2981x over previous
//
#include <hip/hip_runtime.h>
#include <hip/hip_bf16.h>
#include <math.h>

// EnvelopeWassersteinLoss: n=m=8192, d=64, EPS=0.05, 20 Sinkhorn iterations.
//   prep:     XP,XQ f32 -> bf16 + row sq-norms
//   gemm_max: MFMA GEMM -> per-block max -> bm[]; per-(colchunk,row) min -> rminpart
//   max_red:  bm[4096] -> reg, inv_reg
//   scale2:   rminpart -> mnrow[i] (exact row min of C), rs[i] = exp(-mn/reg)
//   gemm_K:   GEMM again, L_ij = round((C-mn_i)/step) byte, step = reg*18/255
//             decode: K_ij = rs_i * LUT[L], LUT[L] = exp(-L*18/255), LUT[255]=0
//             => C~ = mn_i + L*step is EXACTLY -reg*ln(K~): self-consistent.
//   20x:      matvecT (y_part = K^T u; rs folds into u), reduce_v (v=b/y),
//             matvecR (A_i = sum LUT[L] v_j; last iter also B_i = sum L*LUT[L] v_j)
//   final:    loss = (1/N) * sum_i (mn_i + step * B_i/A_i)   (rs cancels)

#define NN 8192
#define DD 64
#define EPSV 0.05f
#define NITER 20
#define LSTEP 0.070588235f      /* 18/255: exponent step per code */
#define K1FACT 14.166666667f    /* 255/18: codes per unit of C/reg */

typedef __attribute__((ext_vector_type(8))) short short8;   // 8 x bf16
typedef __attribute__((ext_vector_type(4))) float fx4;

__device__ inline unsigned short f2bf(float f) {
    union { float f; unsigned int i; } x; x.f = f;
    unsigned int r = x.i + 0x7fffu + ((x.i >> 16) & 1u);
    return (unsigned short)(r >> 16);
}

// ---------------- prep: convert + row norms ----------------
__global__ __launch_bounds__(256) void prep_k(const float* __restrict__ XP,
                                              const float* __restrict__ XQ,
                                              unsigned short* __restrict__ XPb,
                                              unsigned short* __restrict__ XQb,
                                              float* __restrict__ pn,
                                              float* __restrict__ qn) {
    int task = blockIdx.x * 4 + (threadIdx.x >> 6);
    int lane = threadIdx.x & 63;
    const float* src; unsigned short* dst; float* nrm; int row;
    if (task < NN) { src = XP; dst = XPb; nrm = pn; row = task; }
    else           { src = XQ; dst = XQb; nrm = qn; row = task - NN; }
    float xv = src[row * DD + lane];
    dst[row * DD + lane] = f2bf(xv);
    float s = xv * xv;
    #pragma unroll
    for (int o = 32; o; o >>= 1) s += __shfl_xor(s, o);
    if (lane == 0) nrm[row] = s;
}

// ---------------- shared GEMM tile: wave computes 64x64 via 4x4 MFMA frags ----------------
__device__ inline void gemm_tile(const unsigned short* __restrict__ XPb,
                                 const unsigned short* __restrict__ XQb,
                                 int R0, int C0, int lane, fx4 acc[4][4]) {
    int r  = lane & 15;
    int ko = (lane >> 4) * 8;
    #pragma unroll
    for (int kk = 0; kk < DD; kk += 32) {
        short8 a[4], b[4];
        #pragma unroll
        for (int m = 0; m < 4; m++)
            a[m] = *(const short8*)(XPb + (R0 + m * 16 + r) * DD + kk + ko);
        #pragma unroll
        for (int n = 0; n < 4; n++)
            b[n] = *(const short8*)(XQb + (C0 + n * 16 + r) * DD + kk + ko);
        #pragma unroll
        for (int m = 0; m < 4; m++)
            #pragma unroll
            for (int n = 0; n < 4; n++)
                acc[m][n] = __builtin_amdgcn_mfma_f32_16x16x32_bf16(a[m], b[n], acc[m][n], 0, 0, 0);
    }
}

// ---------------- pass 1: per-block max of C -> bm[]; per-(cchunk,row) min -> rminpart ----------------
__global__ __launch_bounds__(256) void gemm_max_k(const unsigned short* __restrict__ XPb,
                                                  const unsigned short* __restrict__ XQb,
                                                  const float* __restrict__ pn,
                                                  const float* __restrict__ qn,
                                                  float* __restrict__ bm,
                                                  float* __restrict__ rminpart) {
    int w = threadIdx.x >> 6, wr = w >> 1, wc = w & 1;
    int lane = threadIdx.x & 63;
    int R0 = blockIdx.y * 128 + wr * 64;
    int C0 = blockIdx.x * 128 + wc * 64;
    fx4 acc[4][4] = {};
    gemm_tile(XPb, XQb, R0, C0, lane, acc);

    float pl = pn[R0 + lane], ql = qn[C0 + lane];
    float pr[16], qc[4];
    #pragma unroll
    for (int m = 0; m < 4; m++)
        #pragma unroll
        for (int j = 0; j < 4; j++)
            pr[m * 4 + j] = __shfl(pl, m * 16 + ((lane >> 4) << 2) + j);
    #pragma unroll
    for (int n = 0; n < 4; n++) qc[n] = __shfl(ql, n * 16 + (lane & 15));

    float mx = 0.0f;
    float mn[16];
    #pragma unroll
    for (int m = 0; m < 4; m++) {
        #pragma unroll
        for (int j = 0; j < 4; j++) {
            float lmn = 1e30f;
            #pragma unroll
            for (int n = 0; n < 4; n++) {
                float c = fmaxf(pr[m * 4 + j] + qc[n] - 2.0f * acc[m][n][j], 0.0f);
                mx = fmaxf(mx, c);
                lmn = fminf(lmn, c);
            }
            mn[m * 4 + j] = lmn;
        }
    }
    // per-row min across the 16 lanes sharing this hi-group (same rows, different cols)
    #pragma unroll
    for (int o = 1; o < 16; o <<= 1) {
        #pragma unroll
        for (int e = 0; e < 16; e++) mn[e] = fminf(mn[e], __shfl_xor(mn[e], o));
    }
    if ((lane & 15) == 0) {
        int hi = lane >> 4;
        int cchunk = blockIdx.x * 2 + wc;      // 128 chunks of 64 cols
        #pragma unroll
        for (int m = 0; m < 4; m++)
            #pragma unroll
            for (int j = 0; j < 4; j++)
                rminpart[(size_t)cchunk * NN + blockIdx.y * 128 + wr * 64 + m * 16 + hi * 4 + j]
                    = mn[m * 4 + j];
    }

    #pragma unroll
    for (int o = 32; o; o >>= 1) mx = fmaxf(mx, __shfl_xor(mx, o));
    __shared__ float wmax[4];
    if (lane == 0) wmax[w] = mx;
    __syncthreads();
    if (threadIdx.x == 0)
        bm[blockIdx.y * 64 + blockIdx.x] = fmaxf(fmaxf(wmax[0], wmax[1]), fmaxf(wmax[2], wmax[3]));
}

// ---------------- reduce bm[4096] -> regbuf {reg, inv_reg} ----------------
__global__ __launch_bounds__(256) void max_red_k(const float* __restrict__ bm,
                                                 float* __restrict__ regbuf) {
    int t = threadIdx.x;
    float mx = 0.0f;
    #pragma unroll
    for (int i = 0; i < 16; ++i) mx = fmaxf(mx, bm[i * 256 + t]);
    #pragma unroll
    for (int o = 32; o; o >>= 1) mx = fmaxf(mx, __shfl_xor(mx, o));
    __shared__ float wmax[4];
    if ((t & 63) == 0) wmax[t >> 6] = mx;
    __syncthreads();
    if (t == 0) {
        float m = fmaxf(fmaxf(wmax[0], wmax[1]), fmaxf(wmax[2], wmax[3]));
        float reg = EPSV * m;
        regbuf[0] = reg;
        regbuf[1] = 1.0f / reg;
    }
}

// ---------------- per-row min + rs = exp(-mn/reg) ----------------
__global__ __launch_bounds__(256) void scale2_k(const float* __restrict__ rminpart,
                                                const float* __restrict__ regbuf,
                                                float* __restrict__ mnrow,
                                                float* __restrict__ rs) {
    int row = blockIdx.x * 256 + threadIdx.x;
    float mn = 1e30f;
    #pragma unroll 8
    for (int c = 0; c < 128; ++c) mn = fminf(mn, rminpart[(size_t)c * NN + row]);
    mnrow[row] = mn;
    rs[row] = __expf(-mn * regbuf[1]);
}

// ---------------- pass 2: L = round((C-mn)/step) byte, coalesced ----------------
__global__ __launch_bounds__(256) void gemm_K_k(const unsigned short* __restrict__ XPb,
                                                const unsigned short* __restrict__ XQb,
                                                const float* __restrict__ pn,
                                                const float* __restrict__ qn,
                                                const float* __restrict__ regbuf,
                                                const float* __restrict__ mnrow,
                                                unsigned char* __restrict__ Kb) {
    __shared__ unsigned char tile[128][136];   // byte tile; rows 8B-aligned
    int w = threadIdx.x >> 6, wr = w >> 1, wc = w & 1;
    int lane = threadIdx.x & 63;
    int R0 = blockIdx.y * 128 + wr * 64;
    int C0 = blockIdx.x * 128 + wc * 64;
    fx4 acc[4][4] = {};
    gemm_tile(XPb, XQb, R0, C0, lane, acc);

    float k1 = regbuf[1] * K1FACT;             // codes per C-unit
    float pl = pn[R0 + lane], ql = qn[C0 + lane];
    float mnl = mnrow[R0 + lane];
    float pr[16], qc[4], mnr[16];
    #pragma unroll
    for (int m = 0; m < 4; m++)
        #pragma unroll
        for (int j = 0; j < 4; j++) {
            int src = m * 16 + ((lane >> 4) << 2) + j;
            pr[m * 4 + j]  = __shfl(pl, src);
            mnr[m * 4 + j] = __shfl(mnl, src);
        }
    #pragma unroll
    for (int n = 0; n < 4; n++) qc[n] = __shfl(ql, n * 16 + (lane & 15));

    #pragma unroll
    for (int m = 0; m < 4; m++) {
        #pragma unroll
        for (int n = 0; n < 4; n++) {
            #pragma unroll
            for (int j = 0; j < 4; j++) {
                float c = fmaxf(pr[m * 4 + j] + qc[n] - 2.0f * acc[m][n][j], 0.0f);
                int L = (int)(fmaf(c - mnr[m * 4 + j], k1, 0.5f));   // c >= mn exactly
                L = L > 255 ? 255 : L;
                int lr = wr * 64 + m * 16 + ((lane >> 4) << 2) + j;
                int lc = wc * 64 + n * 16 + (lane & 15);
                tile[lr][lc] = (unsigned char)L;
            }
        }
    }
    __syncthreads();

    int lane16 = threadIdx.x & 15;
    int rowgrp = threadIdx.x >> 4;
    size_t Rg = (size_t)blockIdx.y * 128;
    int Cg = blockIdx.x * 128;
    #pragma unroll
    for (int s = 0; s < 8; ++s) {
        int row = s * 16 + rowgrp;
        uint2 pk = *(const uint2*)&tile[row][lane16 * 8];
        *(uint2*)(Kb + (Rg + row) * NN + Cg + lane16 * 8) = pk;
    }
}

// ---------------- y_part[c][j] = sum_{i in 64-row chunk c} rs_i*LUT[L_ij] * u_i ----------------
__global__ __launch_bounds__(256) void matvecT_k(const unsigned char* __restrict__ Kb,
                                                 const float* __restrict__ xA,
                                                 const float* __restrict__ rs,
                                                 float* __restrict__ y_part, int iter) {
    __shared__ float us[64];
    __shared__ float lut_s[256];
    int t = threadIdx.x;
    int r0 = blockIdx.y * 64;
    lut_s[t] = (t == 255) ? 0.0f : __expf(-(float)t * LSTEP);
    if (t < 64) {
        float u = 1.0f / (float)NN;
        // u_i * rs_i; for iter>0, u_i = (1/N)/(rs_i*A_i) so rs cancels.
        us[t] = (iter == 0) ? u * rs[r0 + t] : u / xA[r0 + t];
    }
    __syncthreads();

    int col0 = blockIdx.x * 2048 + t * 8;
    float a0 = 0, a1 = 0, a2 = 0, a3 = 0, a4 = 0, a5 = 0, a6 = 0, a7 = 0;
    const unsigned char* base = Kb + (size_t)r0 * NN + col0;
    #pragma unroll 4
    for (int rr = 0; rr < 64; ++rr) {
        uint2 kb = *(const uint2*)(base + (size_t)rr * NN);
        float u = us[rr];
        a0 += lut_s[kb.x & 255u]         * u;
        a1 += lut_s[(kb.x >> 8) & 255u]  * u;
        a2 += lut_s[(kb.x >> 16) & 255u] * u;
        a3 += lut_s[kb.x >> 24]          * u;
        a4 += lut_s[kb.y & 255u]         * u;
        a5 += lut_s[(kb.y >> 8) & 255u]  * u;
        a6 += lut_s[(kb.y >> 16) & 255u] * u;
        a7 += lut_s[kb.y >> 24]          * u;
    }
    float* yp = y_part + (size_t)blockIdx.y * NN + col0;
    fx4 s0 = {a0, a1, a2, a3};
    fx4 s1 = {a4, a5, a6, a7};
    *(fx4*)(yp)     = s0;
    *(fx4*)(yp + 4) = s1;
}

// ---------------- v[j] = b / sum_c y_part[c][j]  (128 chunks) ----------------
__global__ __launch_bounds__(256) void reduce_v_k(const float* __restrict__ y_part,
                                                  float* __restrict__ vv) {
    int t = threadIdx.x;
    int w = t >> 6;
    int j = blockIdx.x * 64 + (t & 63);
    float s = 0.0f;
    #pragma unroll 8
    for (int c = 0; c < 32; ++c)
        s += y_part[(size_t)(w * 32 + c) * NN + j];
    __shared__ float part[4][64];
    part[w][t & 63] = s;
    __syncthreads();
    if (t < 64) {
        float y = part[0][t] + part[1][t] + part[2][t] + part[3][t];
        vv[blockIdx.x * 64 + t] = (1.0f / (float)NN) / y;
    }
}

// ---------------- A_i = sum_j LUT[L] v_j (xA); last iter: B_i = sum_j L*LUT[L] v_j, tt = B/A ----------------
__global__ __launch_bounds__(256) void matvecR_k(const unsigned char* __restrict__ Kb,
                                                 const float* __restrict__ vv,
                                                 float* __restrict__ xA,
                                                 float* __restrict__ tt, int last) {
    __shared__ float lut_s[256];
    __shared__ float lutc_s[256];
    int t = threadIdx.x;
    {
        float lv = (t == 255) ? 0.0f : __expf(-(float)t * LSTEP);
        lut_s[t] = lv;
        lutc_s[t] = (float)t * lv;
    }
    __syncthreads();

    int w = t >> 6, lane = t & 63;
    int rbase = blockIdx.x * 16 + w * 4;
    for (int rr = 0; rr < 4; ++rr) {
        int i = rbase + rr;
        const unsigned char* Krow = Kb + (size_t)i * NN;
        float acc = 0.0f, acc2 = 0.0f;
        #pragma unroll 2
        for (int p = 0; p < 8; ++p) {
            int c0 = p * 1024 + lane * 16;
            uint4 kb = *(const uint4*)(Krow + c0);
            fx4 v0 = *(const fx4*)(vv + c0);
            fx4 v1 = *(const fx4*)(vv + c0 + 4);
            fx4 v2 = *(const fx4*)(vv + c0 + 8);
            fx4 v3 = *(const fx4*)(vv + c0 + 12);
            unsigned int ix[16];
            ix[0]  = kb.x & 255u; ix[1]  = (kb.x >> 8) & 255u;
            ix[2]  = (kb.x >> 16) & 255u; ix[3]  = kb.x >> 24;
            ix[4]  = kb.y & 255u; ix[5]  = (kb.y >> 8) & 255u;
            ix[6]  = (kb.y >> 16) & 255u; ix[7]  = kb.y >> 24;
            ix[8]  = kb.z & 255u; ix[9]  = (kb.z >> 8) & 255u;
            ix[10] = (kb.z >> 16) & 255u; ix[11] = kb.z >> 24;
            ix[12] = kb.w & 255u; ix[13] = (kb.w >> 8) & 255u;
            ix[14] = (kb.w >> 16) & 255u; ix[15] = kb.w >> 24;
            if (last) {
                #pragma unroll
                for (int e = 0; e < 4; e++) {
                    acc  += lut_s[ix[e]] * v0[e] + lut_s[ix[e + 4]] * v1[e]
                          + lut_s[ix[e + 8]] * v2[e] + lut_s[ix[e + 12]] * v3[e];
                    acc2 += lutc_s[ix[e]] * v0[e] + lutc_s[ix[e + 4]] * v1[e]
                          + lutc_s[ix[e + 8]] * v2[e] + lutc_s[ix[e + 12]] * v3[e];
                }
            } else {
                #pragma unroll
                for (int e = 0; e < 4; e++)
                    acc += lut_s[ix[e]] * v0[e] + lut_s[ix[e + 4]] * v1[e]
                         + lut_s[ix[e + 8]] * v2[e] + lut_s[ix[e + 12]] * v3[e];
            }
        }
        #pragma unroll
        for (int o = 32; o; o >>= 1) acc += __shfl_xor(acc, o);
        if (last) {
            #pragma unroll
            for (int o = 32; o; o >>= 1) acc2 += __shfl_xor(acc2, o);
        }
        if (lane == 0) {
            xA[i] = acc;
            if (last) tt[i] = acc2 / acc;
        }
    }
}

// ---------------- loss = (1/N) * sum_i (mn_i + step * tt_i),  step = reg*18/255 ----------------
__global__ __launch_bounds__(256) void final_loss_k(const float* __restrict__ mnrow,
                                                    const float* __restrict__ tt,
                                                    const float* __restrict__ regbuf,
                                                    float* __restrict__ out) {
    int t = threadIdx.x;
    float step = regbuf[0] * LSTEP;
    float s = 0.0f;
    for (int i = t; i < NN; i += 256)
        s += mnrow[i] + step * tt[i];
    #pragma unroll
    for (int o = 32; o; o >>= 1) s += __shfl_xor(s, o);
    __shared__ float wsum[4];
    if ((t & 63) == 0) wsum[t >> 6] = s;
    __syncthreads();
    if (t == 0)
        out[0] = (wsum[0] + wsum[1] + wsum[2] + wsum[3]) / (float)NN;
}

extern "C" void kernel_launch(void* const* d_in, const int* in_sizes, int n_in,
                              void* d_out, int out_size, void* d_ws, size_t ws_size,
                              hipStream_t stream) {
    const float* XP = (const float*)d_in[0];
    const float* XQ = (const float*)d_in[1];
    float* out = (float*)d_out;

    // workspace layout (~74.5 MiB)
    char* p = (char*)d_ws;
    unsigned char* Kb = (unsigned char*)p;     p += (size_t)NN * NN;        // 64 MiB
    unsigned short* XPb = (unsigned short*)p;  p += (size_t)NN * DD * 2;    // 1 MiB
    unsigned short* XQb = (unsigned short*)p;  p += (size_t)NN * DD * 2;    // 1 MiB
    float* y_part = (float*)p;                 p += (size_t)128 * NN * 4;   // 4 MiB
    float* rminpart = (float*)p;               p += (size_t)128 * NN * 4;   // 4 MiB
    float* pn = (float*)p;                     p += NN * 4;
    float* qn = (float*)p;                     p += NN * 4;
    float* xA = (float*)p;                     p += NN * 4;
    float* vv = (float*)p;                     p += NN * 4;
    float* tt = (float*)p;                     p += NN * 4;
    float* mnrow = (float*)p;                  p += NN * 4;
    float* rs = (float*)p;                     p += NN * 4;
    float* bm = (float*)p;                     p += 4096 * 4;
    float* regbuf = (float*)p;

    prep_k<<<4096, 256, 0, stream>>>(XP, XQ, XPb, XQb, pn, qn);
    gemm_max_k<<<dim3(64, 64), 256, 0, stream>>>(XPb, XQb, pn, qn, bm, rminpart);
    max_red_k<<<1, 256, 0, stream>>>(bm, regbuf);
    scale2_k<<<32, 256, 0, stream>>>(rminpart, regbuf, mnrow, rs);
    gemm_K_k<<<dim3(64, 64), 256, 0, stream>>>(XPb, XQb, pn, qn, regbuf, mnrow, Kb);

    for (int it = 0; it < NITER; ++it) {
        matvecT_k<<<dim3(4, 128), 256, 0, stream>>>(Kb, xA, rs, y_part, it);
        reduce_v_k<<<128, 256, 0, stream>>>(y_part, vv);
        matvecR_k<<<512, 256, 0, stream>>>(Kb, vv, xA, tt, (it == NITER - 1) ? 1 : 0);
    }
    final_loss_k<<<1, 256, 0, stream>>>(mnrow, tt, regbuf, out);
}